// Round 18
// baseline (337.278 us; speedup 1.0000x reference)
//
#include <hip/hip_runtime.h>
#include <hip/hip_bf16.h>

#define BB 4
#define TT 1024
#define EE 1024
#define HH 16
#define DD 64

typedef unsigned short ushort_t;
typedef unsigned int uint_t;
typedef __attribute__((ext_vector_type(8))) short short8;
typedef __attribute__((ext_vector_type(4))) float f32x4;

__device__ __forceinline__ ushort_t f2bf(float f) {
  uint_t u = __float_as_uint(f);
  u += 0x7fffu + ((u >> 16) & 1u);
  return (ushort_t)(u >> 16);
}
__device__ __forceinline__ float bf2f(ushort_t s) {
  return __uint_as_float(((uint_t)s) << 16);
}

// async global->LDS, 16B per lane; dst is wave-uniform base (HW adds lane*16)
__device__ __forceinline__ void gload16(const ushort_t* src, ushort_t* dst) {
  __builtin_amdgcn_global_load_lds(
      (const __attribute__((address_space(1))) void*)src,
      (__attribute__((address_space(3))) void*)dst, 16, 0, 0);
}

// ---------------------------------------------------------------------------
// fused fp32 -> bf16 convert for x (blocks 0..2047) and pos (2048..2559)
// ---------------------------------------------------------------------------
__global__ void __launch_bounds__(256) conv_flat2(
    const float* __restrict__ x, const float* __restrict__ pos,
    ushort_t* __restrict__ ox, ushort_t* __restrict__ opos) {
  int bid = blockIdx.x;
  const float* in;
  ushort_t* out;
  int i;
  if (bid < 2048) { in = x; out = ox; i = (bid * 256 + threadIdx.x) * 8; }
  else { in = pos; out = opos; i = ((bid - 2048) * 256 + threadIdx.x) * 8; }
  float4 a = *(const float4*)(in + i);
  float4 b = *(const float4*)(in + i + 4);
  uint4 o;
  o.x = (uint_t)f2bf(a.x) | ((uint_t)f2bf(a.y) << 16);
  o.y = (uint_t)f2bf(a.z) | ((uint_t)f2bf(a.w) << 16);
  o.z = (uint_t)f2bf(b.x) | ((uint_t)f2bf(b.y) << 16);
  o.w = (uint_t)f2bf(b.z) | ((uint_t)f2bf(b.w) << 16);
  *(uint4*)(out + i) = o;
}

// ---------------------------------------------------------------------------
// transpose + convert, 5 weights in one launch (z selects): O[n][k]=bf16(W[k][n])
// ---------------------------------------------------------------------------
__global__ void __launch_bounds__(256) trans_conv5(
    const float* __restrict__ W0, const float* __restrict__ W1,
    const float* __restrict__ W2, const float* __restrict__ W3,
    const float* __restrict__ W4,
    ushort_t* __restrict__ O0, ushort_t* __restrict__ O1,
    ushort_t* __restrict__ O2, ushort_t* __restrict__ O3,
    ushort_t* __restrict__ O4) {
  const float* W; ushort_t* Oh;
  switch (blockIdx.z) {
    case 0: W = W0; Oh = O0; break;
    case 1: W = W1; Oh = O1; break;
    case 2: W = W2; Oh = O2; break;
    case 3: W = W3; Oh = O3; break;
    default: W = W4; Oh = O4; break;
  }
  __shared__ float Ts[64][65];
  const int n0 = blockIdx.x * 64, k0 = blockIdx.y * 64;
  const int t = threadIdx.x;
  const int r = t >> 2, cs = (t & 3) * 16;
  const float* src = W + (size_t)(k0 + r) * 1024 + n0 + cs;
  #pragma unroll
  for (int e = 0; e < 16; e += 4) {
    float4 v4 = *(const float4*)(src + e);
    Ts[r][cs + e] = v4.x; Ts[r][cs + e + 1] = v4.y;
    Ts[r][cs + e + 2] = v4.z; Ts[r][cs + e + 3] = v4.w;
  }
  __syncthreads();
  ushort_t hb[16];
  #pragma unroll
  for (int e = 0; e < 16; e++) hb[e] = f2bf(Ts[cs + e][r]);
  ushort_t* dh = Oh + (size_t)(n0 + r) * 1024 + k0 + cs;
  *(uint4*)dh = *(const uint4*)hb;
  *(uint4*)(dh + 8) = *(const uint4*)(hb + 8);
}

// ---------------------------------------------------------------------------
// MFMA GEMM (m97 structure), qkv + r folded into ONE launch, grid (32,32)
// ---------------------------------------------------------------------------
__global__ void __launch_bounds__(256) mfma_gemm_proj(
    const ushort_t* __restrict__ Ax, const ushort_t* __restrict__ Ap,
    const ushort_t* __restrict__ B0, const ushort_t* __restrict__ B1,
    const ushort_t* __restrict__ B2, const ushort_t* __restrict__ B3,
    ushort_t* __restrict__ o_qu, ushort_t* __restrict__ o_qv,
    ushort_t* __restrict__ o_k, ushort_t* __restrict__ o_v,
    ushort_t* __restrict__ o_r,
    const float* __restrict__ bias_u, const float* __restrict__ bias_v) {
  __shared__ ushort_t sA[2][128 * 32];
  __shared__ ushort_t sB[2][128 * 32];
  const int tid = threadIdx.x;
  const int w = tid >> 6, lane = tid & 63, g = lane >> 4, cl = lane & 15;
  const int wr = w >> 1, wc = w & 1;

  int widx, n0l;
  const ushort_t* Bt;
  const ushort_t* A;
  if (blockIdx.x < 24) {
    widx = blockIdx.x >> 3;
    n0l = (blockIdx.x & 7) * 128;
    Bt = (widx == 0) ? B0 : ((widx == 1) ? B1 : B2);
    A = Ax;
  } else {
    widx = 3;
    n0l = (blockIdx.x - 24) * 128;
    Bt = B3;
    A = Ap;
  }
  const int m0 = blockIdx.y * 128;
  if (widx == 3 && m0 >= 1024) return;   // r has M=1024 only

  f32x4 acc[4][4];
  #pragma unroll
  for (int fi = 0; fi < 4; fi++)
    #pragma unroll
    for (int fj = 0; fj < 4; fj++) acc[fi][fj] = (f32x4){0.f, 0.f, 0.f, 0.f};

  auto STAGE = [&](int buf, int t) {
    const int k0b = t * 64;
    #pragma unroll
    for (int i = 0; i < 2; i++) {
      int cb = w * 128 + i * 64;
      int c = cb + lane;
      const char* sa = (const char*)A + (size_t)(m0 + (c >> 2)) * 2048 + k0b + (c & 3) * 16;
      gload16((const ushort_t*)sa, &sA[buf][cb * 8]);
      const char* sb = (const char*)Bt + (size_t)(n0l + (c >> 2)) * 2048 + k0b + (c & 3) * 16;
      gload16((const ushort_t*)sb, &sB[buf][cb * 8]);
    }
  };

  STAGE(0, 0);
  __syncthreads();
  int cur = 0;
  for (int t = 0; t < 32; t++) {
    if (t + 1 < 32) STAGE(cur ^ 1, t + 1);
    short8 af[4], bfr[4];
    #pragma unroll
    for (int f = 0; f < 4; f++) {
      af[f] = *(const short8*)&sA[cur][(wr * 64 + f * 16 + cl) * 32 + g * 8];
      bfr[f] = *(const short8*)&sB[cur][(wc * 64 + f * 16 + cl) * 32 + g * 8];
    }
    #pragma unroll
    for (int fi = 0; fi < 4; fi++)
      #pragma unroll
      for (int fj = 0; fj < 4; fj++)
        acc[fi][fj] = __builtin_amdgcn_mfma_f32_16x16x32_bf16(af[fi], bfr[fj], acc[fi][fj], 0, 0, 0);
    __syncthreads();
    cur ^= 1;
  }

  #pragma unroll
  for (int fi = 0; fi < 4; fi++)
    #pragma unroll
    for (int fj = 0; fj < 4; fj++)
      #pragma unroll
      for (int reg = 0; reg < 4; reg++) {
        int m = m0 + wr * 64 + fi * 16 + 4 * g + reg;
        int n = n0l + wc * 64 + fj * 16 + cl;
        float val = acc[fi][fj][reg];
        int h = n >> 6, d = n & 63;
        if (widx == 0) {
          int b = m >> 10, tt = m & 1023;
          size_t idx = (((size_t)(b * HH + h)) * TT + tt) * DD + d;
          float s = val * 0.125f;
          o_qu[idx] = f2bf(s + bias_u[n]);
          o_qv[idx] = f2bf(s + bias_v[n]);
        } else if (widx == 1) {
          int b = m >> 10, tt = m & 1023;
          size_t idx = (((size_t)(b * HH + h)) * TT + tt) * DD + d;
          o_k[idx] = f2bf(val);
        } else if (widx == 2) {
          int b = m >> 10, tt = m & 1023;
          size_t idx = (((size_t)(b * HH + h)) * DD + d) * TT + tt;  // v^T
          o_v[idx] = f2bf(val);
        } else {
          size_t idx = ((size_t)h * TT + m) * DD + d;
          o_r[idx] = f2bf(val);
        }
      }
}

// ---------------------------------------------------------------------------
// Split-bf16 merge GEMM, 2-pass: out = (Ah+Al) @ Wh^T + b
// ---------------------------------------------------------------------------
__global__ void __launch_bounds__(256) mfma_gemm_merge(
    const ushort_t* __restrict__ Ah, const ushort_t* __restrict__ Al,
    const ushort_t* __restrict__ Bh,
    const float* __restrict__ bias, float* __restrict__ out) {
  __shared__ ushort_t sAh[2][128 * 32], sAl[2][128 * 32];
  __shared__ ushort_t sBh[2][128 * 32];
  const int tid = threadIdx.x;
  const int w = tid >> 6, lane = tid & 63, g = lane >> 4, cl = lane & 15;
  const int wr = w >> 1, wc = w & 1;
  const int n0l = blockIdx.x * 128;
  const int m0 = blockIdx.y * 128;

  f32x4 acc[4][4];
  #pragma unroll
  for (int fi = 0; fi < 4; fi++)
    #pragma unroll
    for (int fj = 0; fj < 4; fj++) acc[fi][fj] = (f32x4){0.f, 0.f, 0.f, 0.f};

  auto STAGE = [&](int buf, int t) {
    const int k0b = t * 64;
    #pragma unroll
    for (int i = 0; i < 2; i++) {
      int cb = w * 128 + i * 64;
      int c = cb + lane;
      size_t offA = (size_t)(m0 + (c >> 2)) * 2048 + k0b + (c & 3) * 16;
      size_t offB = (size_t)(n0l + (c >> 2)) * 2048 + k0b + (c & 3) * 16;
      gload16((const ushort_t*)((const char*)Ah + offA), &sAh[buf][cb * 8]);
      gload16((const ushort_t*)((const char*)Al + offA), &sAl[buf][cb * 8]);
      gload16((const ushort_t*)((const char*)Bh + offB), &sBh[buf][cb * 8]);
    }
  };

  STAGE(0, 0);
  __syncthreads();
  int cur = 0;
  for (int t = 0; t < 32; t++) {
    if (t + 1 < 32) STAGE(cur ^ 1, t + 1);
    short8 ah[4], al[4], bh[4];
    #pragma unroll
    for (int f = 0; f < 4; f++) {
      int ra = (wr * 64 + f * 16 + cl) * 32 + g * 8;
      int rb = (wc * 64 + f * 16 + cl) * 32 + g * 8;
      ah[f] = *(const short8*)&sAh[cur][ra];
      al[f] = *(const short8*)&sAl[cur][ra];
      bh[f] = *(const short8*)&sBh[cur][rb];
    }
    #pragma unroll
    for (int fi = 0; fi < 4; fi++)
      #pragma unroll
      for (int fj = 0; fj < 4; fj++) {
        acc[fi][fj] = __builtin_amdgcn_mfma_f32_16x16x32_bf16(ah[fi], bh[fj], acc[fi][fj], 0, 0, 0);
        acc[fi][fj] = __builtin_amdgcn_mfma_f32_16x16x32_bf16(al[fi], bh[fj], acc[fi][fj], 0, 0, 0);
      }
    __syncthreads();
    cur ^= 1;
  }

  #pragma unroll
  for (int fi = 0; fi < 4; fi++)
    #pragma unroll
    for (int fj = 0; fj < 4; fj++)
      #pragma unroll
      for (int reg = 0; reg < 4; reg++) {
        int m = m0 + wr * 64 + fi * 16 + 4 * g + reg;
        int n = n0l + wc * 64 + fj * 16 + cl;
        out[(size_t)m * 1024 + n] = acc[fi][fj][reg] + bias[n];
      }
}

// ---------------------------------------------------------------------------
// Tile staging: 8 rows (1KB) of a [64][64 bf16] LDS tile from rows of global
// stride `rstride` (elements), XOR bank-swizzle pre-applied on the GLOBAL
// source (LDS linear). swizzled read: byte_in_row' = byte ^ ((row&7)<<4)
// ---------------------------------------------------------------------------
__device__ __forceinline__ void stage8s(ushort_t* region, const ushort_t* grow0,
                                        int rstride, int r0, int lane) {
  int flat16 = r0 * 8 + lane;
  int row = flat16 >> 3;
  int ch = flat16 & 7;
  const ushort_t* src = grow0 + (size_t)row * rstride + ((((ch << 4) ^ ((row & 7) << 4))) >> 1);
  gload16(src, region + r0 * 64);
}

__device__ __forceinline__ short8 ldsw(const ushort_t* base, int row, int offB) {
  const char* p = (const char*)base + row * 128 + (offB ^ ((row & 7) << 4));
  return *(const short8*)p;
}

// ---------------------------------------------------------------------------
// MFMA flash attention = r16 (168 us) + counted-vmcnt r-prefetch (T4):
// the first 3 r-load pairs issue right after the K stage; vmcnt(6) releases
// the wave when the 8 OLDEST (K) loads land, leaving the 6 r loads in flight
// under QK. sched_barrier(0) fences pin issue order (gload_lds vs plain
// loads) so the count is exact. Diagonal tiles keep the vmcnt(0) path.
// rel_shift(i,j): j<=i -> qv[i].r[T-1+j-i]; j==i+1 -> 0; j>=i+2 -> qv[i+1].r[j-i-2]
// ---------------------------------------------------------------------------
__global__ void __launch_bounds__(256) attn_mfma_kernel(
    const ushort_t* __restrict__ qu_g, const ushort_t* __restrict__ qv_g,
    const ushort_t* __restrict__ k_g, const ushort_t* __restrict__ vt_g,
    const ushort_t* __restrict__ r_g,
    ushort_t* __restrict__ att_h, ushort_t* __restrict__ att_l)
{
    __shared__ ushort_t sK[4][64 * 64];    // per-WAVE K tile (swizzled rows), 32 KB
    __shared__ ushort_t sG[4][2304];       // per-wave G (stride 18) / P (stride 72)

    const int tid = threadIdx.x;
    const int w = tid >> 6;
    const int lane = tid & 63;
    const int g = lane >> 4;
    const int cl = lane & 15;

    // XCD-aware remap: all 16 i-blocks of a (b,h) on one XCD (bijective)
    const int lid = blockIdx.x + 16 * blockIdx.y + 256 * blockIdx.z;
    const int xcd = lid & 7, seq = lid >> 3;
    const int bhg = xcd * 8 + (seq >> 4);
    const int i0 = (seq & 15) * 64;
    const int h = bhg & 15;
    const int b = bhg >> 4;
    const size_t base_bh = ((size_t)(b * HH + h)) * TT * DD;
    const ushort_t* rh = r_g + (size_t)h * TT * DD;
    const ushort_t* vtb = vt_g + base_bh;

    ushort_t* sKw = sK[w];
    ushort_t* Gw = sG[w];
    ushort_t* Pb = sG[w];

    // ---- Q fragments in registers (one-time global/L2 reads) ----
    const int qrow = i0 + 16 * w + cl;
    const ushort_t* qup = qu_g + base_bh + (size_t)qrow * 64;
    short8 aQ0 = *(const short8*)(qup + 8 * g);
    short8 aQ1 = *(const short8*)(qup + 32 + 8 * g);
    const ushort_t* qv1p = qv_g + base_bh + (size_t)qrow * 64;
    short8 aV0 = *(const short8*)(qv1p + 8 * g);
    short8 aV1 = *(const short8*)(qv1p + 32 + 8 * g);
    int r2row = qrow + 1; if (r2row > 1023) r2row = 1023;  // clamped row never gathered
    const ushort_t* qv2p = qv_g + base_bh + (size_t)r2row * 64;
    short8 aV0s = *(const short8*)(qv2p + 8 * g);
    short8 aV1s = *(const short8*)(qv2p + 32 + 8 * g);

    // per-wave K staging: whole 64x64 tile into this wave's private region
    auto STAGE = [&](int jt16) {
      const ushort_t* kb = k_g + base_bh + (size_t)(jt16 * 64) * 64;
      #pragma unroll
      for (int r0 = 0; r0 < 64; r0 += 8)
        stage8s(sKw, kb, 64, r0, lane);
    };

    // r-fragment load / G-store helpers (named vars only -> no scratch)
    auto RLD = [&](int base, int s, short8& A, short8& B) {
      const ushort_t* rp = rh + (size_t)(base + s * 16 + cl) * 64 + 8 * g;
      A = *(const short8*)rp;
      B = *(const short8*)(rp + 32);
    };
    auto GST = [&](int s, short8 A, short8 B, short8 X0, short8 X1) {
      f32x4 ga = (f32x4){0.f, 0.f, 0.f, 0.f};
      ga = __builtin_amdgcn_mfma_f32_16x16x32_bf16(X0, A, ga, 0, 0, 0);
      ga = __builtin_amdgcn_mfma_f32_16x16x32_bf16(X1, B, ga, 0, 0, 0);
      int m = s * 16 + cl;
      *(uint_t*)(Gw + m * 18 + 4 * g) =
          (uint_t)f2bf(ga[0]) | ((uint_t)f2bf(ga[1]) << 16);
      *(uint_t*)(Gw + m * 18 + 4 * g + 2) =
          (uint_t)f2bf(ga[2]) | ((uint_t)f2bf(ga[3]) << 16);
    };

    f32x4 Oa[4];
    #pragma unroll
    for (int q = 0; q < 4; q++) Oa[q] = (f32x4){0.f, 0.f, 0.f, 0.f};
    float lrun[4] = {0.f, 0.f, 0.f, 0.f};

    for (int jt16 = 0; jt16 < 16; jt16++) {
        const int j0 = jt16 * 64;
        const int dji = j0 - i0;
        // branch-uniform rel-window base (nondiag paths)
        int pre_base = 0;
        if (dji < 0) pre_base = 1008 + dji - 16 * w;           // rr in [0,1023]
        else if (dji > 0) { pre_base = dji - 17 - 16 * w; if (pre_base < 0) pre_base = 0; }

        // ---- stage K tile; issue first 3 r-pairs; counted wait ----
        STAGE(jt16);
        __builtin_amdgcn_sched_barrier(0);
        short8 a0, b0, a1, b1, a2, b2;
        if (dji != 0) {
            RLD(pre_base, 0, a0, b0);
            RLD(pre_base, 1, a1, b1);
            RLD(pre_base, 2, a2, b2);
            asm volatile("s_waitcnt vmcnt(6)" ::: "memory");   // 8 K loads done, 6 r in flight
        } else {
            asm volatile("s_waitcnt vmcnt(0)" ::: "memory");
        }
        __builtin_amdgcn_sched_barrier(0);

        // ---- content scores: S = Qu @ K^T ----
        f32x4 sacc[4];
        #pragma unroll
        for (int jt = 0; jt < 4; jt++) sacc[jt] = (f32x4){0.f, 0.f, 0.f, 0.f};
        __builtin_amdgcn_s_setprio(1);
        #pragma unroll
        for (int jt = 0; jt < 4; jt++) {
            int krow = jt * 16 + cl;
            short8 kb0 = ldsw(sKw, krow, 16 * g);
            short8 kb1 = ldsw(sKw, krow, 64 + 16 * g);
            sacc[jt] = __builtin_amdgcn_mfma_f32_16x16x32_bf16(aQ0, kb0, sacc[jt], 0, 0, 0);
            sacc[jt] = __builtin_amdgcn_mfma_f32_16x16x32_bf16(aQ1, kb1, sacc[jt], 0, 0, 0);
        }
        __builtin_amdgcn_s_setprio(0);

        // ---- rel term: windowed G GEMM (preloaded head, pipelined) + gather ----
        if (dji < 0) {
            GST(0, a0, b0, aV0, aV1); RLD(pre_base, 3, a0, b0);
            GST(1, a1, b1, aV0, aV1); RLD(pre_base, 4, a1, b1);
            GST(2, a2, b2, aV0, aV1);
            GST(3, a0, b0, aV0, aV1);
            GST(4, a1, b1, aV0, aV1);
            // guard-free gather: m1' = 15 + j_local - (4g+reg), w cancels
            #pragma unroll
            for (int jt = 0; jt < 4; jt++)
                #pragma unroll
                for (int reg = 0; reg < 4; reg++) {
                    int m1p = 15 + jt * 16 + cl - 4 * g - reg;
                    sacc[jt][reg] += bf2f(Gw[m1p * 18 + 4 * g + reg]);
                }
        } else if (dji > 0) {
            GST(0, a0, b0, aV0s, aV1s); RLD(pre_base, 3, a0, b0);
            GST(1, a1, b1, aV0s, aV1s); RLD(pre_base, 4, a1, b1);
            GST(2, a2, b2, aV0s, aV1s);
            GST(3, a0, b0, aV0s, aV1s);
            GST(4, a1, b1, aV0s, aV1s);
            #pragma unroll
            for (int jt = 0; jt < 4; jt++)
                #pragma unroll
                for (int reg = 0; reg < 4; reg++) {
                    int dlt = dji + jt * 16 + cl - 16 * w - 4 * g - reg;
                    int idx2 = dlt - 2 - pre_base;
                    if (dlt >= 2) sacc[jt][reg] += bf2f(Gw[idx2 * 18 + 4 * g + reg]);
                }
        } else {
            // diagonal tile: verified two-branch path (Gw / disjoint Gw2)
            ushort_t* Gw2 = Gw + 64 * 18;
            for (int sub = 0; sub < 4; sub++) {
                int m = sub * 16 + cl;
                const ushort_t* rp = rh + (size_t)(960 + m) * 64 + 8 * g;
                f32x4 gacc = (f32x4){0.f, 0.f, 0.f, 0.f};
                gacc = __builtin_amdgcn_mfma_f32_16x16x32_bf16(aV0, *(const short8*)rp, gacc, 0, 0, 0);
                gacc = __builtin_amdgcn_mfma_f32_16x16x32_bf16(aV1, *(const short8*)(rp + 32), gacc, 0, 0, 0);
                *(uint_t*)(Gw + m * 18 + 4 * g) =
                    (uint_t)f2bf(gacc[0]) | ((uint_t)f2bf(gacc[1]) << 16);
                *(uint_t*)(Gw + m * 18 + 4 * g + 2) =
                    (uint_t)f2bf(gacc[2]) | ((uint_t)f2bf(gacc[3]) << 16);
            }
            for (int sub = 0; sub < 4; sub++) {
                int m = sub * 16 + cl;
                const ushort_t* rp = rh + (size_t)m * 64 + 8 * g;
                f32x4 gacc = (f32x4){0.f, 0.f, 0.f, 0.f};
                gacc = __builtin_amdgcn_mfma_f32_16x16x32_bf16(aV0s, *(const short8*)rp, gacc, 0, 0, 0);
                gacc = __builtin_amdgcn_mfma_f32_16x16x32_bf16(aV1s, *(const short8*)(rp + 32), gacc, 0, 0, 0);
                *(uint_t*)(Gw2 + m * 18 + 4 * g) =
                    (uint_t)f2bf(gacc[0]) | ((uint_t)f2bf(gacc[1]) << 16);
                *(uint_t*)(Gw2 + m * 18 + 4 * g + 2) =
                    (uint_t)f2bf(gacc[2]) | ((uint_t)f2bf(gacc[3]) << 16);
            }
            #pragma unroll
            for (int jt = 0; jt < 4; jt++)
                #pragma unroll
                for (int reg = 0; reg < 4; reg++) {
                    int m1 = 63 + jt * 16 + cl - 16 * w - 4 * g - reg;
                    if (m1 <= 63) sacc[jt][reg] += bf2f(Gw[m1 * 18 + 4 * g + reg]);
                }
            #pragma unroll
            for (int jt = 0; jt < 4; jt++)
                #pragma unroll
                for (int reg = 0; reg < 4; reg++) {
                    int dlt = jt * 16 + cl - 16 * w - 4 * g - reg;
                    if (dlt >= 2) sacc[jt][reg] += bf2f(Gw2[(dlt - 2) * 18 + 4 * g + reg]);
                }
        }

        // ---- softmax numerator (no max subtraction; logits bounded ~|8|) ----
        #pragma unroll
        for (int reg = 0; reg < 4; reg++) {
            #pragma unroll
            for (int jt = 0; jt < 4; jt++) {
                float p = __expf(sacc[jt][reg]);
                lrun[reg] += p;
                Pb[(4 * g + reg) * 72 + jt * 16 + cl] = f2bf(p);
            }
        }

        // ---- PV: O += P @ V  (V^T fragments direct from L2) ----
        __builtin_amdgcn_s_setprio(1);
        #pragma unroll
        for (int kk = 0; kk < 2; kk++) {
            short8 aP = *(const short8*)((const char*)Pb + cl * 144 + 64 * kk + 16 * g);
            #pragma unroll
            for (int q = 0; q < 4; q++) {
                const ushort_t* vp = vtb + (size_t)(q * 16 + cl) * 1024
                                     + j0 + kk * 32 + 8 * g;
                short8 bV = *(const short8*)vp;
                Oa[q] = __builtin_amdgcn_mfma_f32_16x16x32_bf16(aP, bV, Oa[q], 0, 0, 0);
            }
        }
        __builtin_amdgcn_s_setprio(0);
        // no __syncthreads: sK/sG are wave-private; in-wave lgkm/vm ordering
    }

    // ---- epilogue: one row-sum reduce, normalize, hi/lo split, store ----
    float inv[4];
    #pragma unroll
    for (int reg = 0; reg < 4; reg++) {
        float s = lrun[reg];
        #pragma unroll
        for (int msk = 1; msk <= 8; msk <<= 1) s += __shfl_xor(s, msk);
        inv[reg] = 1.f / s;
    }
    #pragma unroll
    for (int q = 0; q < 4; q++)
        #pragma unroll
        for (int reg = 0; reg < 4; reg++) {
            int i = i0 + 16 * w + 4 * g + reg;
            int d = q * 16 + cl;
            float val = Oa[q][reg] * inv[reg];
            ushort_t hi = f2bf(val);
            ushort_t lo = f2bf(val - bf2f(hi));
            size_t oi = (((size_t)(b * TT + i)) * HH + h) * DD + d;
            att_h[oi] = hi;
            att_l[oi] = lo;
        }
}

extern "C" void kernel_launch(void* const* d_in, const int* in_sizes, int n_in,
                              void* d_out, int out_size, void* d_ws, size_t ws_size,
                              hipStream_t stream) {
    const float* x    = (const float*)d_in[0];
    const float* pos  = (const float*)d_in[1];
    const float* Wq   = (const float*)d_in[2];
    const float* Wk   = (const float*)d_in[3];
    const float* Wv   = (const float*)d_in[4];
    const float* Wr   = (const float*)d_in[5];
    const float* ub   = (const float*)d_in[6];
    const float* vb   = (const float*)d_in[7];
    const float* mW   = (const float*)d_in[8];
    const float* mb   = (const float*)d_in[9];
    float* out = (float*)d_out;

    const size_t M1 = 1u << 20;
    ushort_t* ws = (ushort_t*)d_ws;
    ushort_t* xb   = ws;
    ushort_t* posb = ws + 4 * M1;
    ushort_t* wqt  = ws + 5 * M1;
    ushort_t* wkt  = ws + 6 * M1;
    ushort_t* wvt  = ws + 7 * M1;
    ushort_t* wrt  = ws + 8 * M1;
    ushort_t* wmh  = ws + 9 * M1;
    ushort_t* qu_g = ws + 11 * M1;
    ushort_t* qv_g = ws + 15 * M1;
    ushort_t* k_g  = ws + 19 * M1;
    ushort_t* vt_g = ws + 23 * M1;   // vt[b,h,d,t]
    ushort_t* r_g  = ws + 27 * M1;
    ushort_t* ath  = ws + 28 * M1;
    ushort_t* atl  = ws + 32 * M1;

    dim3 blk(256);

    hipLaunchKernelGGL(conv_flat2, dim3(2560), blk, 0, stream, x, pos, xb, posb);
    hipLaunchKernelGGL(trans_conv5, dim3(16, 16, 5), blk, 0, stream,
                       Wq, Wk, Wv, Wr, mW, wqt, wkt, wvt, wrt, wmh);

    hipLaunchKernelGGL(mfma_gemm_proj, dim3(32, 32), blk, 0, stream,
                       xb, posb, wqt, wkt, wvt, wrt,
                       qu_g, qv_g, k_g, vt_g, r_g, ub, vb);

    hipLaunchKernelGGL(attn_mfma_kernel, dim3(TT / 64, HH, BB), blk, 0, stream,
                       qu_g, qv_g, k_g, vt_g, r_g, ath, atl);

    hipLaunchKernelGGL(mfma_gemm_merge, dim3(8, 32), blk, 0, stream,
                       ath, atl, wmh, mb, out);
}

// Round 19
// 295.600 us; speedup vs baseline: 1.1410x; 1.1410x over previous
//
#include <hip/hip_runtime.h>
#include <hip/hip_bf16.h>

#define BB 4
#define TT 1024
#define EE 1024
#define HH 16
#define DD 64

typedef unsigned short ushort_t;
typedef unsigned int uint_t;
typedef __attribute__((ext_vector_type(8))) short short8;
typedef __attribute__((ext_vector_type(4))) float f32x4;

__device__ __forceinline__ ushort_t f2bf(float f) {
  uint_t u = __float_as_uint(f);
  u += 0x7fffu + ((u >> 16) & 1u);
  return (ushort_t)(u >> 16);
}
__device__ __forceinline__ float bf2f(ushort_t s) {
  return __uint_as_float(((uint_t)s) << 16);
}

// async global->LDS, 16B per lane; dst is wave-uniform base (HW adds lane*16)
__device__ __forceinline__ void gload16(const ushort_t* src, ushort_t* dst) {
  __builtin_amdgcn_global_load_lds(
      (const __attribute__((address_space(1))) void*)src,
      (__attribute__((address_space(3))) void*)dst, 16, 0, 0);
}

// ---------------------------------------------------------------------------
// fused fp32 -> bf16 convert for x (blocks 0..2047) and pos (2048..2559)
// ---------------------------------------------------------------------------
__global__ void __launch_bounds__(256) conv_flat2(
    const float* __restrict__ x, const float* __restrict__ pos,
    ushort_t* __restrict__ ox, ushort_t* __restrict__ opos) {
  int bid = blockIdx.x;
  const float* in;
  ushort_t* out;
  int i;
  if (bid < 2048) { in = x; out = ox; i = (bid * 256 + threadIdx.x) * 8; }
  else { in = pos; out = opos; i = ((bid - 2048) * 256 + threadIdx.x) * 8; }
  float4 a = *(const float4*)(in + i);
  float4 b = *(const float4*)(in + i + 4);
  uint4 o;
  o.x = (uint_t)f2bf(a.x) | ((uint_t)f2bf(a.y) << 16);
  o.y = (uint_t)f2bf(a.z) | ((uint_t)f2bf(a.w) << 16);
  o.z = (uint_t)f2bf(b.x) | ((uint_t)f2bf(b.y) << 16);
  o.w = (uint_t)f2bf(b.z) | ((uint_t)f2bf(b.w) << 16);
  *(uint4*)(out + i) = o;
}

// ---------------------------------------------------------------------------
// transpose + convert, 5 weights in one launch (z selects): O[n][k]=bf16(W[k][n])
// ---------------------------------------------------------------------------
__global__ void __launch_bounds__(256) trans_conv5(
    const float* __restrict__ W0, const float* __restrict__ W1,
    const float* __restrict__ W2, const float* __restrict__ W3,
    const float* __restrict__ W4,
    ushort_t* __restrict__ O0, ushort_t* __restrict__ O1,
    ushort_t* __restrict__ O2, ushort_t* __restrict__ O3,
    ushort_t* __restrict__ O4) {
  const float* W; ushort_t* Oh;
  switch (blockIdx.z) {
    case 0: W = W0; Oh = O0; break;
    case 1: W = W1; Oh = O1; break;
    case 2: W = W2; Oh = O2; break;
    case 3: W = W3; Oh = O3; break;
    default: W = W4; Oh = O4; break;
  }
  __shared__ float Ts[64][65];
  const int n0 = blockIdx.x * 64, k0 = blockIdx.y * 64;
  const int t = threadIdx.x;
  const int r = t >> 2, cs = (t & 3) * 16;
  const float* src = W + (size_t)(k0 + r) * 1024 + n0 + cs;
  #pragma unroll
  for (int e = 0; e < 16; e += 4) {
    float4 v4 = *(const float4*)(src + e);
    Ts[r][cs + e] = v4.x; Ts[r][cs + e + 1] = v4.y;
    Ts[r][cs + e + 2] = v4.z; Ts[r][cs + e + 3] = v4.w;
  }
  __syncthreads();
  ushort_t hb[16];
  #pragma unroll
  for (int e = 0; e < 16; e++) hb[e] = f2bf(Ts[cs + e][r]);
  ushort_t* dh = Oh + (size_t)(n0 + r) * 1024 + k0 + cs;
  *(uint4*)dh = *(const uint4*)hb;
  *(uint4*)(dh + 8) = *(const uint4*)(hb + 8);
}

// ---------------------------------------------------------------------------
// MFMA GEMM (m97 structure), qkv + r folded into ONE launch, grid (32,32):
//  bx<24: fused qkv on A=xb (widx=bx>>3: 0 qu/qv dual, 1 k, 2 v^T)
//  bx>=24: r on A=posb, n0l=(bx-24)*128, only by<8 active
// ---------------------------------------------------------------------------
__global__ void __launch_bounds__(256) mfma_gemm_proj(
    const ushort_t* __restrict__ Ax, const ushort_t* __restrict__ Ap,
    const ushort_t* __restrict__ B0, const ushort_t* __restrict__ B1,
    const ushort_t* __restrict__ B2, const ushort_t* __restrict__ B3,
    ushort_t* __restrict__ o_qu, ushort_t* __restrict__ o_qv,
    ushort_t* __restrict__ o_k, ushort_t* __restrict__ o_v,
    ushort_t* __restrict__ o_r,
    const float* __restrict__ bias_u, const float* __restrict__ bias_v) {
  __shared__ ushort_t sA[2][128 * 32];
  __shared__ ushort_t sB[2][128 * 32];
  const int tid = threadIdx.x;
  const int w = tid >> 6, lane = tid & 63, g = lane >> 4, cl = lane & 15;
  const int wr = w >> 1, wc = w & 1;

  int widx, n0l;
  const ushort_t* Bt;
  const ushort_t* A;
  if (blockIdx.x < 24) {
    widx = blockIdx.x >> 3;
    n0l = (blockIdx.x & 7) * 128;
    Bt = (widx == 0) ? B0 : ((widx == 1) ? B1 : B2);
    A = Ax;
  } else {
    widx = 3;
    n0l = (blockIdx.x - 24) * 128;
    Bt = B3;
    A = Ap;
  }
  const int m0 = blockIdx.y * 128;
  if (widx == 3 && m0 >= 1024) return;   // r has M=1024 only

  f32x4 acc[4][4];
  #pragma unroll
  for (int fi = 0; fi < 4; fi++)
    #pragma unroll
    for (int fj = 0; fj < 4; fj++) acc[fi][fj] = (f32x4){0.f, 0.f, 0.f, 0.f};

  auto STAGE = [&](int buf, int t) {
    const int k0b = t * 64;
    #pragma unroll
    for (int i = 0; i < 2; i++) {
      int cb = w * 128 + i * 64;
      int c = cb + lane;
      const char* sa = (const char*)A + (size_t)(m0 + (c >> 2)) * 2048 + k0b + (c & 3) * 16;
      gload16((const ushort_t*)sa, &sA[buf][cb * 8]);
      const char* sb = (const char*)Bt + (size_t)(n0l + (c >> 2)) * 2048 + k0b + (c & 3) * 16;
      gload16((const ushort_t*)sb, &sB[buf][cb * 8]);
    }
  };

  STAGE(0, 0);
  __syncthreads();
  int cur = 0;
  for (int t = 0; t < 32; t++) {
    if (t + 1 < 32) STAGE(cur ^ 1, t + 1);
    short8 af[4], bfr[4];
    #pragma unroll
    for (int f = 0; f < 4; f++) {
      af[f] = *(const short8*)&sA[cur][(wr * 64 + f * 16 + cl) * 32 + g * 8];
      bfr[f] = *(const short8*)&sB[cur][(wc * 64 + f * 16 + cl) * 32 + g * 8];
    }
    #pragma unroll
    for (int fi = 0; fi < 4; fi++)
      #pragma unroll
      for (int fj = 0; fj < 4; fj++)
        acc[fi][fj] = __builtin_amdgcn_mfma_f32_16x16x32_bf16(af[fi], bfr[fj], acc[fi][fj], 0, 0, 0);
    __syncthreads();
    cur ^= 1;
  }

  #pragma unroll
  for (int fi = 0; fi < 4; fi++)
    #pragma unroll
    for (int fj = 0; fj < 4; fj++)
      #pragma unroll
      for (int reg = 0; reg < 4; reg++) {
        int m = m0 + wr * 64 + fi * 16 + 4 * g + reg;
        int n = n0l + wc * 64 + fj * 16 + cl;
        float val = acc[fi][fj][reg];
        int h = n >> 6, d = n & 63;
        if (widx == 0) {
          int b = m >> 10, tt = m & 1023;
          size_t idx = (((size_t)(b * HH + h)) * TT + tt) * DD + d;
          float s = val * 0.125f;
          o_qu[idx] = f2bf(s + bias_u[n]);
          o_qv[idx] = f2bf(s + bias_v[n]);
        } else if (widx == 1) {
          int b = m >> 10, tt = m & 1023;
          size_t idx = (((size_t)(b * HH + h)) * TT + tt) * DD + d;
          o_k[idx] = f2bf(val);
        } else if (widx == 2) {
          int b = m >> 10, tt = m & 1023;
          size_t idx = (((size_t)(b * HH + h)) * DD + d) * TT + tt;  // v^T
          o_v[idx] = f2bf(val);
        } else {
          size_t idx = ((size_t)h * TT + m) * DD + d;
          o_r[idx] = f2bf(val);
        }
      }
}

// ---------------------------------------------------------------------------
// Split-bf16 merge GEMM, 2-pass: out = (Ah+Al) @ Wh^T + b
// ---------------------------------------------------------------------------
__global__ void __launch_bounds__(256) mfma_gemm_merge(
    const ushort_t* __restrict__ Ah, const ushort_t* __restrict__ Al,
    const ushort_t* __restrict__ Bh,
    const float* __restrict__ bias, float* __restrict__ out) {
  __shared__ ushort_t sAh[2][128 * 32], sAl[2][128 * 32];
  __shared__ ushort_t sBh[2][128 * 32];
  const int tid = threadIdx.x;
  const int w = tid >> 6, lane = tid & 63, g = lane >> 4, cl = lane & 15;
  const int wr = w >> 1, wc = w & 1;
  const int n0l = blockIdx.x * 128;
  const int m0 = blockIdx.y * 128;

  f32x4 acc[4][4];
  #pragma unroll
  for (int fi = 0; fi < 4; fi++)
    #pragma unroll
    for (int fj = 0; fj < 4; fj++) acc[fi][fj] = (f32x4){0.f, 0.f, 0.f, 0.f};

  auto STAGE = [&](int buf, int t) {
    const int k0b = t * 64;
    #pragma unroll
    for (int i = 0; i < 2; i++) {
      int cb = w * 128 + i * 64;
      int c = cb + lane;
      size_t offA = (size_t)(m0 + (c >> 2)) * 2048 + k0b + (c & 3) * 16;
      size_t offB = (size_t)(n0l + (c >> 2)) * 2048 + k0b + (c & 3) * 16;
      gload16((const ushort_t*)((const char*)Ah + offA), &sAh[buf][cb * 8]);
      gload16((const ushort_t*)((const char*)Al + offA), &sAl[buf][cb * 8]);
      gload16((const ushort_t*)((const char*)Bh + offB), &sBh[buf][cb * 8]);
    }
  };

  STAGE(0, 0);
  __syncthreads();
  int cur = 0;
  for (int t = 0; t < 32; t++) {
    if (t + 1 < 32) STAGE(cur ^ 1, t + 1);
    short8 ah[4], al[4], bh[4];
    #pragma unroll
    for (int f = 0; f < 4; f++) {
      int ra = (wr * 64 + f * 16 + cl) * 32 + g * 8;
      int rb = (wc * 64 + f * 16 + cl) * 32 + g * 8;
      ah[f] = *(const short8*)&sAh[cur][ra];
      al[f] = *(const short8*)&sAl[cur][ra];
      bh[f] = *(const short8*)&sBh[cur][rb];
    }
    #pragma unroll
    for (int fi = 0; fi < 4; fi++)
      #pragma unroll
      for (int fj = 0; fj < 4; fj++) {
        acc[fi][fj] = __builtin_amdgcn_mfma_f32_16x16x32_bf16(ah[fi], bh[fj], acc[fi][fj], 0, 0, 0);
        acc[fi][fj] = __builtin_amdgcn_mfma_f32_16x16x32_bf16(al[fi], bh[fj], acc[fi][fj], 0, 0, 0);
      }
    __syncthreads();
    cur ^= 1;
  }

  #pragma unroll
  for (int fi = 0; fi < 4; fi++)
    #pragma unroll
    for (int fj = 0; fj < 4; fj++)
      #pragma unroll
      for (int reg = 0; reg < 4; reg++) {
        int m = m0 + wr * 64 + fi * 16 + 4 * g + reg;
        int n = n0l + wc * 64 + fj * 16 + cl;
        out[(size_t)m * 1024 + n] = acc[fi][fj][reg] + bias[n];
      }
}

// ---------------------------------------------------------------------------
// Tile staging: 8 rows (1KB) of a [64][64 bf16] LDS tile from rows of global
// stride `rstride` (elements), XOR bank-swizzle pre-applied on the GLOBAL
// source (LDS linear). swizzled read: byte_in_row' = byte ^ ((row&7)<<4)
// ---------------------------------------------------------------------------
__device__ __forceinline__ void stage8s(ushort_t* region, const ushort_t* grow0,
                                        int rstride, int r0, int lane) {
  int flat16 = r0 * 8 + lane;
  int row = flat16 >> 3;
  int ch = flat16 & 7;
  const ushort_t* src = grow0 + (size_t)row * rstride + ((((ch << 4) ^ ((row & 7) << 4))) >> 1);
  gload16(src, region + r0 * 64);
}

__device__ __forceinline__ short8 ldsw(const ushort_t* base, int row, int offB) {
  const char* p = (const char*)base + row * 128 + (offB ^ ((row & 7) << 4));
  return *(const short8*)p;
}

// ---------------------------------------------------------------------------
// MFMA flash attention (round-16 proven config, 168 us, VGPR 120, occ 22%):
// exact rel_shift, per-wave K staging via global_load_lds, no barriers,
// PV reads V^T fragments direct from L2 at PV time. Register-budget rule
// learned r15/r18: any ILP-adding prefetch crossing 128 VGPRs halves
// occupancy and regresses -- keep this kernel <=128 VGPRs.
// rel_shift(i,j): j<=i -> qv[i].r[T-1+j-i]; j==i+1 -> 0; j>=i+2 -> qv[i+1].r[j-i-2]
// ---------------------------------------------------------------------------
__global__ void __launch_bounds__(256) attn_mfma_kernel(
    const ushort_t* __restrict__ qu_g, const ushort_t* __restrict__ qv_g,
    const ushort_t* __restrict__ k_g, const ushort_t* __restrict__ vt_g,
    const ushort_t* __restrict__ r_g,
    ushort_t* __restrict__ att_h, ushort_t* __restrict__ att_l)
{
    __shared__ ushort_t sK[4][64 * 64];    // per-WAVE K tile (swizzled rows), 32 KB
    __shared__ ushort_t sG[4][2304];       // per-wave G (stride 18) / P (stride 72)

    const int tid = threadIdx.x;
    const int w = tid >> 6;
    const int lane = tid & 63;
    const int g = lane >> 4;
    const int cl = lane & 15;

    // XCD-aware remap: all 16 i-blocks of a (b,h) on one XCD (bijective)
    const int lid = blockIdx.x + 16 * blockIdx.y + 256 * blockIdx.z;
    const int xcd = lid & 7, seq = lid >> 3;
    const int bhg = xcd * 8 + (seq >> 4);
    const int i0 = (seq & 15) * 64;
    const int h = bhg & 15;
    const int b = bhg >> 4;
    const size_t base_bh = ((size_t)(b * HH + h)) * TT * DD;
    const ushort_t* rh = r_g + (size_t)h * TT * DD;
    const ushort_t* vtb = vt_g + base_bh;

    ushort_t* sKw = sK[w];
    ushort_t* Gw = sG[w];
    ushort_t* Pb = sG[w];

    // ---- Q fragments in registers (one-time global/L2 reads) ----
    const int qrow = i0 + 16 * w + cl;
    const ushort_t* qup = qu_g + base_bh + (size_t)qrow * 64;
    short8 aQ0 = *(const short8*)(qup + 8 * g);
    short8 aQ1 = *(const short8*)(qup + 32 + 8 * g);
    const ushort_t* qv1p = qv_g + base_bh + (size_t)qrow * 64;
    short8 aV0 = *(const short8*)(qv1p + 8 * g);
    short8 aV1 = *(const short8*)(qv1p + 32 + 8 * g);
    int r2row = qrow + 1; if (r2row > 1023) r2row = 1023;  // clamped row never gathered
    const ushort_t* qv2p = qv_g + base_bh + (size_t)r2row * 64;
    short8 aV0s = *(const short8*)(qv2p + 8 * g);
    short8 aV1s = *(const short8*)(qv2p + 32 + 8 * g);

    // per-wave K staging: whole 64x64 tile into this wave's private region
    auto STAGE = [&](int jt16) {
      const ushort_t* kb = k_g + base_bh + (size_t)(jt16 * 64) * 64;
      #pragma unroll
      for (int r0 = 0; r0 < 64; r0 += 8)
        stage8s(sKw, kb, 64, r0, lane);
    };

    // r-fragment load / G-store helpers (named vars only -> no scratch)
    auto RLD = [&](int base, int s, short8& A, short8& B) {
      const ushort_t* rp = rh + (size_t)(base + s * 16 + cl) * 64 + 8 * g;
      A = *(const short8*)rp;
      B = *(const short8*)(rp + 32);
    };
    auto GST = [&](int s, short8 A, short8 B, short8 X0, short8 X1) {
      f32x4 ga = (f32x4){0.f, 0.f, 0.f, 0.f};
      ga = __builtin_amdgcn_mfma_f32_16x16x32_bf16(X0, A, ga, 0, 0, 0);
      ga = __builtin_amdgcn_mfma_f32_16x16x32_bf16(X1, B, ga, 0, 0, 0);
      int m = s * 16 + cl;
      *(uint_t*)(Gw + m * 18 + 4 * g) =
          (uint_t)f2bf(ga[0]) | ((uint_t)f2bf(ga[1]) << 16);
      *(uint_t*)(Gw + m * 18 + 4 * g + 2) =
          (uint_t)f2bf(ga[2]) | ((uint_t)f2bf(ga[3]) << 16);
    };

    f32x4 Oa[4];
    #pragma unroll
    for (int q = 0; q < 4; q++) Oa[q] = (f32x4){0.f, 0.f, 0.f, 0.f};
    float lrun[4] = {0.f, 0.f, 0.f, 0.f};

    for (int jt16 = 0; jt16 < 16; jt16++) {
        const int j0 = jt16 * 64;
        const int dji = j0 - i0;

        // ---- stage this wave's K tile; wave-level wait (no barrier) ----
        STAGE(jt16);
        asm volatile("s_waitcnt vmcnt(0)" ::: "memory");
        __builtin_amdgcn_sched_barrier(0);

        // ---- content scores: S = Qu @ K^T ----
        f32x4 sacc[4];
        #pragma unroll
        for (int jt = 0; jt < 4; jt++) sacc[jt] = (f32x4){0.f, 0.f, 0.f, 0.f};
        __builtin_amdgcn_s_setprio(1);
        #pragma unroll
        for (int jt = 0; jt < 4; jt++) {
            int krow = jt * 16 + cl;
            short8 b0 = ldsw(sKw, krow, 16 * g);
            short8 b1 = ldsw(sKw, krow, 64 + 16 * g);
            sacc[jt] = __builtin_amdgcn_mfma_f32_16x16x32_bf16(aQ0, b0, sacc[jt], 0, 0, 0);
            sacc[jt] = __builtin_amdgcn_mfma_f32_16x16x32_bf16(aQ1, b1, sacc[jt], 0, 0, 0);
        }
        __builtin_amdgcn_s_setprio(0);

        // ---- rel term: windowed G GEMM (3-deep pipelined loads) + gather ----
        if (dji < 0) {
            const int cbase1w = 1008 + dji - 16 * w;   // rr in [0,1023]
            short8 a0, b0, a1, b1, a2, b2;
            RLD(cbase1w, 0, a0, b0);
            RLD(cbase1w, 1, a1, b1);
            RLD(cbase1w, 2, a2, b2);
            GST(0, a0, b0, aV0, aV1); RLD(cbase1w, 3, a0, b0);
            GST(1, a1, b1, aV0, aV1); RLD(cbase1w, 4, a1, b1);
            GST(2, a2, b2, aV0, aV1);
            GST(3, a0, b0, aV0, aV1);
            GST(4, a1, b1, aV0, aV1);
            // guard-free gather: m1' = 15 + j_local - (4g+reg), w cancels
            #pragma unroll
            for (int jt = 0; jt < 4; jt++)
                #pragma unroll
                for (int reg = 0; reg < 4; reg++) {
                    int m1p = 15 + jt * 16 + cl - 4 * g - reg;
                    sacc[jt][reg] += bf2f(Gw[m1p * 18 + 4 * g + reg]);
                }
        } else if (dji > 0) {
            int rbase2w = dji - 17 - 16 * w;
            if (rbase2w < 0) rbase2w = 0;
            short8 a0, b0, a1, b1, a2, b2;
            RLD(rbase2w, 0, a0, b0);
            RLD(rbase2w, 1, a1, b1);
            RLD(rbase2w, 2, a2, b2);
            GST(0, a0, b0, aV0s, aV1s); RLD(rbase2w, 3, a0, b0);
            GST(1, a1, b1, aV0s, aV1s); RLD(rbase2w, 4, a1, b1);
            GST(2, a2, b2, aV0s, aV1s);
            GST(3, a0, b0, aV0s, aV1s);
            GST(4, a1, b1, aV0s, aV1s);
            #pragma unroll
            for (int jt = 0; jt < 4; jt++)
                #pragma unroll
                for (int reg = 0; reg < 4; reg++) {
                    int dlt = dji + jt * 16 + cl - 16 * w - 4 * g - reg;
                    int idx2 = dlt - 2 - rbase2w;
                    if (dlt >= 2) sacc[jt][reg] += bf2f(Gw[idx2 * 18 + 4 * g + reg]);
                }
        } else {
            // diagonal tile: verified two-branch path (Gw / disjoint Gw2)
            ushort_t* Gw2 = Gw + 64 * 18;
            for (int sub = 0; sub < 4; sub++) {
                int m = sub * 16 + cl;
                const ushort_t* rp = rh + (size_t)(960 + m) * 64 + 8 * g;
                f32x4 gacc = (f32x4){0.f, 0.f, 0.f, 0.f};
                gacc = __builtin_amdgcn_mfma_f32_16x16x32_bf16(aV0, *(const short8*)rp, gacc, 0, 0, 0);
                gacc = __builtin_amdgcn_mfma_f32_16x16x32_bf16(aV1, *(const short8*)(rp + 32), gacc, 0, 0, 0);
                *(uint_t*)(Gw + m * 18 + 4 * g) =
                    (uint_t)f2bf(gacc[0]) | ((uint_t)f2bf(gacc[1]) << 16);
                *(uint_t*)(Gw + m * 18 + 4 * g + 2) =
                    (uint_t)f2bf(gacc[2]) | ((uint_t)f2bf(gacc[3]) << 16);
            }
            for (int sub = 0; sub < 4; sub++) {
                int m = sub * 16 + cl;
                const ushort_t* rp = rh + (size_t)m * 64 + 8 * g;
                f32x4 gacc = (f32x4){0.f, 0.f, 0.f, 0.f};
                gacc = __builtin_amdgcn_mfma_f32_16x16x32_bf16(aV0s, *(const short8*)rp, gacc, 0, 0, 0);
                gacc = __builtin_amdgcn_mfma_f32_16x16x32_bf16(aV1s, *(const short8*)(rp + 32), gacc, 0, 0, 0);
                *(uint_t*)(Gw2 + m * 18 + 4 * g) =
                    (uint_t)f2bf(gacc[0]) | ((uint_t)f2bf(gacc[1]) << 16);
                *(uint_t*)(Gw2 + m * 18 + 4 * g + 2) =
                    (uint_t)f2bf(gacc[2]) | ((uint_t)f2bf(gacc[3]) << 16);
            }
            #pragma unroll
            for (int jt = 0; jt < 4; jt++)
                #pragma unroll
                for (int reg = 0; reg < 4; reg++) {
                    int m1 = 63 + jt * 16 + cl - 16 * w - 4 * g - reg;
                    if (m1 <= 63) sacc[jt][reg] += bf2f(Gw[m1 * 18 + 4 * g + reg]);
                }
            #pragma unroll
            for (int jt = 0; jt < 4; jt++)
                #pragma unroll
                for (int reg = 0; reg < 4; reg++) {
                    int dlt = jt * 16 + cl - 16 * w - 4 * g - reg;
                    if (dlt >= 2) sacc[jt][reg] += bf2f(Gw2[(dlt - 2) * 18 + 4 * g + reg]);
                }
        }

        // ---- softmax numerator (no max subtraction; logits bounded ~|8|) ----
        #pragma unroll
        for (int reg = 0; reg < 4; reg++) {
            #pragma unroll
            for (int jt = 0; jt < 4; jt++) {
                float p = __expf(sacc[jt][reg]);
                lrun[reg] += p;
                Pb[(4 * g + reg) * 72 + jt * 16 + cl] = f2bf(p);
            }
        }

        // ---- PV: O += P @ V  (V^T fragments direct from L2) ----
        __builtin_amdgcn_s_setprio(1);
        #pragma unroll
        for (int kk = 0; kk < 2; kk++) {
            short8 aP = *(const short8*)((const char*)Pb + cl * 144 + 64 * kk + 16 * g);
            #pragma unroll
            for (int q = 0; q < 4; q++) {
                const ushort_t* vp = vtb + (size_t)(q * 16 + cl) * 1024
                                     + j0 + kk * 32 + 8 * g;
                short8 bV = *(const short8*)vp;
                Oa[q] = __builtin_amdgcn_mfma_f32_16x16x32_bf16(aP, bV, Oa[q], 0, 0, 0);
            }
        }
        __builtin_amdgcn_s_setprio(0);
        // no __syncthreads: sK/sG are wave-private; in-wave lgkm/vm ordering
    }

    // ---- epilogue: one row-sum reduce, normalize, hi/lo split, store ----
    float inv[4];
    #pragma unroll
    for (int reg = 0; reg < 4; reg++) {
        float s = lrun[reg];
        #pragma unroll
        for (int msk = 1; msk <= 8; msk <<= 1) s += __shfl_xor(s, msk);
        inv[reg] = 1.f / s;
    }
    #pragma unroll
    for (int q = 0; q < 4; q++)
        #pragma unroll
        for (int reg = 0; reg < 4; reg++) {
            int i = i0 + 16 * w + 4 * g + reg;
            int d = q * 16 + cl;
            float val = Oa[q][reg] * inv[reg];
            ushort_t hi = f2bf(val);
            ushort_t lo = f2bf(val - bf2f(hi));
            size_t oi = (((size_t)(b * TT + i)) * HH + h) * DD + d;
            att_h[oi] = hi;
            att_l[oi] = lo;
        }
}

extern "C" void kernel_launch(void* const* d_in, const int* in_sizes, int n_in,
                              void* d_out, int out_size, void* d_ws, size_t ws_size,
                              hipStream_t stream) {
    const float* x    = (const float*)d_in[0];
    const float* pos  = (const float*)d_in[1];
    const float* Wq   = (const float*)d_in[2];
    const float* Wk   = (const float*)d_in[3];
    const float* Wv   = (const float*)d_in[4];
    const float* Wr   = (const float*)d_in[5];
    const float* ub   = (const float*)d_in[6];
    const float* vb   = (const float*)d_in[7];
    const float* mW   = (const float*)d_in[8];
    const float* mb   = (const float*)d_in[9];
    float* out = (float*)d_out;

    const size_t M1 = 1u << 20;
    ushort_t* ws = (ushort_t*)d_ws;
    ushort_t* xb   = ws;
    ushort_t* posb = ws + 4 * M1;
    ushort_t* wqt  = ws + 5 * M1;
    ushort_t* wkt  = ws + 6 * M1;
    ushort_t* wvt  = ws + 7 * M1;
    ushort_t* wrt  = ws + 8 * M1;
    ushort_t* wmh  = ws + 9 * M1;
    ushort_t* qu_g = ws + 11 * M1;
    ushort_t* qv_g = ws + 15 * M1;
    ushort_t* k_g  = ws + 19 * M1;
    ushort_t* vt_g = ws + 23 * M1;   // vt[b,h,d,t]
    ushort_t* r_g  = ws + 27 * M1;
    ushort_t* ath  = ws + 28 * M1;
    ushort_t* atl  = ws + 32 * M1;

    dim3 blk(256);

    hipLaunchKernelGGL(conv_flat2, dim3(2560), blk, 0, stream, x, pos, xb, posb);
    hipLaunchKernelGGL(trans_conv5, dim3(16, 16, 5), blk, 0, stream,
                       Wq, Wk, Wv, Wr, mW, wqt, wkt, wvt, wrt, wmh);

    hipLaunchKernelGGL(mfma_gemm_proj, dim3(32, 32), blk, 0, stream,
                       xb, posb, wqt, wkt, wvt, wrt,
                       qu_g, qv_g, k_g, vt_g, r_g, ub, vb);

    hipLaunchKernelGGL(attn_mfma_kernel, dim3(TT / 64, HH, BB), blk, 0, stream,
                       qu_g, qv_g, k_g, vt_g, r_g, ath, atl);

    hipLaunchKernelGGL(mfma_gemm_merge, dim3(8, 32), blk, 0, stream,
                       ath, atl, wmh, mb, out);
}